// Round 5
// baseline (913.499 us; speedup 1.0000x reference)
//
#include <hip/hip_runtime.h>

// HybridMambaBlock pipeline:
//  1) cvt: W_in/W_res/W_out f32 -> bf16 (W_in padded to OPAD rows, zero fill)
//  2) ln: LayerNorm(x) -> xn(bf16); also x -> bf16 for the residual GEMM
//  3) gemm_bt<bf16 out>: p = xn @ W_in^T   (2048 x 52352, the big one)
//  4) gemm_bt<f32 out>:  res = x @ W_res^T
//  5) conv: depthwise causal conv K=4 on u slice of p -> u_conv (f32)
//  6) dt: dt = clip(softplus(dth @ W_dt^T + bias), 1e-4, 1)
//  7) scan v3: chunk-parallel (P=32), lane-owns-d (h[16] in regs, no LDS)
//  8) gate: g = rmsnorm(y*silu(z))*norm_w + res -> bf16
//  9) gemm_bt<f32 out>: out = g @ W_out^T
//
// R4 fixes:
//  - scan1/scan2: __launch_bounds__(256,2). R4's VGPR_Count=48 proved the
//    compiler spilled the prefetch ring to scratch (scan2 WRITE_SIZE 231MB vs
//    12.6MB of y). Cap 2 waves/EU -> 256 VGPR budget -> ring stays in regs.
//  - gemm1: XCD-aware tile remap (each XCD owns ~52 contiguous n-tiles) so a
//    W-slice is fetched into exactly one private L2 (R4 FETCH 325MB = W x4).

typedef unsigned short u16;
typedef __bf16 bf16x8 __attribute__((ext_vector_type(8)));
typedef float f32x4 __attribute__((ext_vector_type(4)));

#define OPAD 52352   // 409*128 >= 52272
#define OTOT 52272
#define DI   1536
#define DM   768
#define Z0   0
#define U0   1536
#define DTH0 3072
#define B0   3120
#define C0   27696

#define SCAN_P 32
#define SCAN_T 32    // 1024 / SCAN_P
#define SPF    4     // prefetch ring depth

__device__ static inline u16 f2bf(float f) {
    unsigned u = __float_as_uint(f);
    u += 0x7fffu + ((u >> 16) & 1u);
    return (u16)(u >> 16);
}
__device__ static inline float bf2f(u16 s) {
    return __uint_as_float(((unsigned)s) << 16);
}

__device__ static inline void gload16(const void* g, void* l) {
    __builtin_amdgcn_global_load_lds(
        (const __attribute__((address_space(1))) unsigned int*)g,
        (__attribute__((address_space(3))) unsigned int*)l, 16, 0, 0);
}

// unpack 8 bf16 (as uint4) -> 8 f32, memory order preserved
__device__ static inline void unpack8(uint4 v, float* f) {
    unsigned w0 = v.x, w1 = v.y, w2 = v.z, w3 = v.w;
    f[0] = __uint_as_float(w0 << 16); f[1] = __uint_as_float(w0 & 0xffff0000u);
    f[2] = __uint_as_float(w1 << 16); f[3] = __uint_as_float(w1 & 0xffff0000u);
    f[4] = __uint_as_float(w2 << 16); f[5] = __uint_as_float(w2 & 0xffff0000u);
    f[6] = __uint_as_float(w3 << 16); f[7] = __uint_as_float(w3 & 0xffff0000u);
}

// ---------------- f32 -> bf16 convert (with zero pad to n_tot) ----------------
__global__ void cvt_kernel(const float* __restrict__ src, u16* __restrict__ dst,
                           long n_src, long n_tot) {
    long i4 = ((long)blockIdx.x * 256 + threadIdx.x) * 4;
    if (i4 >= n_tot) return;
    ushort4 o;
    if (i4 < n_src) {  // n_src is a multiple of 4 for all callers
        float4 v = *(const float4*)(src + i4);
        o.x = f2bf(v.x); o.y = f2bf(v.y); o.z = f2bf(v.z); o.w = f2bf(v.w);
    } else {
        o.x = o.y = o.z = o.w = 0;
    }
    *(ushort4*)(dst + i4) = o;
}

// ---------------- block reduce (sum of two values across 256 threads) --------
__device__ static inline void block_reduce2(float& a, float& b) {
    #pragma unroll
    for (int o = 32; o > 0; o >>= 1) {
        a += __shfl_down(a, o);
        b += __shfl_down(b, o);
    }
    __shared__ float sa[4], sb[4];
    int lane = threadIdx.x & 63, w = threadIdx.x >> 6;
    if (lane == 0) { sa[w] = a; sb[w] = b; }
    __syncthreads();
    a = sa[0] + sa[1] + sa[2] + sa[3];
    b = sb[0] + sb[1] + sb[2] + sb[3];
}

// ---------------- LayerNorm -> xn bf16, plus raw x -> bf16 -------------------
__global__ void __launch_bounds__(256) ln_kernel(const float* __restrict__ x,
        const float* __restrict__ w, const float* __restrict__ b,
        u16* __restrict__ xnbf, u16* __restrict__ xbf) {
    int m = blockIdx.x, tid = threadIdx.x;
    const float* xr = x + (size_t)m * DM;
    float v[3];
    v[0] = xr[tid]; v[1] = xr[tid + 256]; v[2] = xr[tid + 512];
    float s = v[0] + v[1] + v[2];
    float ss = v[0]*v[0] + v[1]*v[1] + v[2]*v[2];
    block_reduce2(s, ss);
    float mu = s * (1.f / DM);
    float var = ss * (1.f / DM) - mu * mu;
    float inv = rsqrtf(var + 1e-5f);
    #pragma unroll
    for (int i = 0; i < 3; ++i) {
        int d = tid + i * 256;
        float xn = (v[i] - mu) * inv * w[d] + b[d];
        xnbf[(size_t)m * DM + d] = f2bf(xn);
        xbf[(size_t)m * DM + d] = f2bf(v[i]);
    }
}

// ---------------- bf16 MFMA GEMM: C[M,N] = A[M,K] * B[N,K]^T -----------------
// 128x128 tile, BK=64, 256 threads (4 waves, each 64x64 via 4x4 of 16x16x32).
// NSWZ=1: XCD-aware remap for the 16x409 grid (launched as 16x416): flat id f
// -> xcd=f&7 owns n-tiles [xcd*52, xcd*52+52); m varies fastest within an XCD
// so 16 consecutive blocks reuse one W-slice from that XCD's L2.
// LDS: XOR-swizzled 16B segments (gather-side permute) -> conflict-free reads.
template <int OUT_BF16, int NSWZ>
__global__ void __launch_bounds__(256) gemm_bt(const u16* __restrict__ A,
        const u16* __restrict__ B, void* __restrict__ C, int K, int ldc) {
    int bx = blockIdx.x, by = blockIdx.y;
    if (NSWZ) {
        int f = by * 16 + bx;
        int xcd = f & 7;
        int local = f >> 3;          // 0..831
        int n = xcd * 52 + (local >> 4);
        if (n >= 409) return;
        bx = local & 15;             // m-tile
        by = n;                      // n-tile
    }
    __shared__ u16 smem[2 * 128 * 64];
    u16* As = smem;
    u16* Bs = smem + 128 * 64;
    int tid = threadIdx.x;
    int m0 = bx * 128, n0 = by * 128;
    int lane = tid & 63, wave = tid >> 6;
    int wm = wave >> 1, wn = wave & 1;
    int l15 = lane & 15, l4 = lane >> 4;
    f32x4 acc[4][4] = {};
    const u16* Ag = A + (size_t)m0 * K;
    const u16* Bg = B + (size_t)n0 * K;
    int crow = tid >> 3;                              // 0..31: row within 32-row group
    int ccol = ((tid & 7) ^ ((tid >> 3) & 7)) * 8;    // swizzled 16B segment
    int ldsoff = (tid & 192) * 16;                    // wave*1024 bytes
    int xr = l15 & 7;                                 // read-side swizzle key

    for (int k0 = 0; k0 < K; k0 += 64) {
        __syncthreads();
        #pragma unroll
        for (int it = 0; it < 4; ++it) {
            gload16(Ag + (size_t)(it * 32 + crow) * K + k0 + ccol,
                    (char*)As + it * 4096 + ldsoff);
            gload16(Bg + (size_t)(it * 32 + crow) * K + k0 + ccol,
                    (char*)Bs + it * 4096 + ldsoff);
        }
        __syncthreads();
        const u16* Arow = As + (wm * 64 + l15) * 64;
        const u16* Brow = Bs + (wn * 64 + l15) * 64;
        #pragma unroll
        for (int kk8 = 0; kk8 < 8; kk8 += 4) {
            int sw = ((l4 + kk8) ^ xr) * 8;
            bf16x8 af[4], bfr[4];
            #pragma unroll
            for (int i = 0; i < 4; ++i) af[i] = *(const bf16x8*)(Arow + i * 16 * 64 + sw);
            #pragma unroll
            for (int j = 0; j < 4; ++j) bfr[j] = *(const bf16x8*)(Brow + j * 16 * 64 + sw);
            #pragma unroll
            for (int i = 0; i < 4; ++i)
                #pragma unroll
                for (int j = 0; j < 4; ++j)
                    acc[i][j] = __builtin_amdgcn_mfma_f32_16x16x32_bf16(
                        af[i], bfr[j], acc[i][j], 0, 0, 0);
        }
    }
    #pragma unroll
    for (int i = 0; i < 4; ++i) {
        int row = m0 + wm * 64 + i * 16 + l4 * 4;
        #pragma unroll
        for (int j = 0; j < 4; ++j) {
            int col = n0 + wn * 64 + j * 16 + l15;
            #pragma unroll
            for (int r = 0; r < 4; ++r) {
                size_t off = (size_t)(row + r) * ldc + col;
                if (OUT_BF16) ((u16*)C)[off] = f2bf(acc[i][j][r]);
                else          ((float*)C)[off] = acc[i][j][r];
            }
        }
    }
}

// ---------------- depthwise causal conv (K=4) --------------------------------
__global__ void __launch_bounds__(256) conv_kernel(const u16* __restrict__ p,
        const float* __restrict__ cw, const float* __restrict__ cb,
        float* __restrict__ u) {
    int d = blockIdx.x * 256 + threadIdx.x;  // 0..1535
    int m = blockIdx.y;                      // 0..2047
    int l = m & 1023;
    int bm = m - l;                          // b*1024
    float acc = cb[d];
    #pragma unroll
    for (int j = 0; j < 4; ++j) {
        int ls = l - 3 + j;
        if (ls >= 0)
            acc += cw[d * 4 + j] * bf2f(p[(size_t)(bm + ls) * OPAD + U0 + d]);
    }
    u[(size_t)m * DI + d] = acc;
}

// ---------------- dt = clip(softplus(dth @ W_dt^T + bias)) -------------------
__global__ void __launch_bounds__(256) dt_kernel(const u16* __restrict__ p,
        const float* __restrict__ Wdt, const float* __restrict__ dt_bias,
        float* __restrict__ dt) {
    int m0 = blockIdx.x * 16, tid = threadIdx.x;
    __shared__ float dth_s[16 * 48];
    for (int i = tid; i < 16 * 48; i += 256)
        dth_s[i] = bf2f(p[(size_t)(m0 + i / 48) * OPAD + DTH0 + (i % 48)]);
    __syncthreads();
    #pragma unroll
    for (int ii = 0; ii < 6; ++ii) {
        int d = ii * 256 + tid;
        float base = dt_bias[d];
        float acc[16];
        #pragma unroll
        for (int mm = 0; mm < 16; ++mm) acc[mm] = base;
        for (int r = 0; r < 48; ++r) {
            float wv = Wdt[d * 48 + r];
            #pragma unroll
            for (int mm = 0; mm < 16; ++mm)
                acc[mm] = fmaf(wv, dth_s[mm * 48 + r], acc[mm]);
        }
        #pragma unroll
        for (int mm = 0; mm < 16; ++mm) {
            float xv = acc[mm];
            float sp = xv > 20.f ? xv : log1pf(__expf(xv));
            sp = fminf(fmaxf(sp, 1e-4f), 1.0f);
            dt[(size_t)(m0 + mm) * DI + d] = sp;
        }
    }
}

// ---------------- scan v3 pass 1: per-chunk (A,h) summaries ------------------
// Lane owns one d-channel; h[16]/A[16] in regs; B reads are per-lane 32B
// contiguous dwordx4 pairs (coalesced across lanes); depth-SPF prefetch ring.
// launch_bounds(256,2): 256-VGPR budget so the ring does NOT spill (R4 bug).
__global__ void __launch_bounds__(256, 2) scan1_kernel(const u16* __restrict__ p,
        const float* __restrict__ dt, const float* __restrict__ u,
        const float* __restrict__ A_log,
        float* __restrict__ chkA, float* __restrict__ chkB) {
    int d = blockIdx.x * 256 + threadIdx.x;
    int b = blockIdx.y, c = blockIdx.z;
    int t0 = c * SCAN_T;
    float a[16];
    #pragma unroll
    for (int n = 0; n < 16; ++n) a[n] = -__expf(A_log[d * 16 + n]);
    const u16* pB = p + (size_t)(b * 1024 + t0) * OPAD + B0 + d * 16;
    const float* dtp = dt + (size_t)(b * 1024 + t0) * DI + d;
    const float* up  = u  + (size_t)(b * 1024 + t0) * DI + d;
    uint4 Br[SPF][2]; float dtr[SPF], ur[SPF];
    #pragma unroll
    for (int i = 0; i < SPF; ++i) {
        Br[i][0] = *(const uint4*)(pB + (size_t)i * OPAD);
        Br[i][1] = *(const uint4*)(pB + (size_t)i * OPAD + 8);
        dtr[i] = dtp[(size_t)i * DI];
        ur[i]  = up[(size_t)i * DI];
    }
    float h[16], Av[16];
    #pragma unroll
    for (int n = 0; n < 16; ++n) { h[n] = 0.f; Av[n] = 1.f; }
    for (int t = 0; t < SCAN_T; ++t) {
        int s = t & (SPF - 1);
        uint4 b0 = Br[s][0], b1 = Br[s][1];
        float dtv = dtr[s], uv = ur[s];
        int tl = t + SPF < SCAN_T ? t + SPF : SCAN_T - 1;
        Br[s][0] = *(const uint4*)(pB + (size_t)tl * OPAD);
        Br[s][1] = *(const uint4*)(pB + (size_t)tl * OPAD + 8);
        dtr[s] = dtp[(size_t)tl * DI];
        ur[s]  = up[(size_t)tl * DI];
        float Bf[16];
        unpack8(b0, Bf); unpack8(b1, Bf + 8);
        float dtu = dtv * uv;
        #pragma unroll
        for (int n = 0; n < 16; ++n) {
            float dA = __expf(dtv * a[n]);
            h[n] = fmaf(dA, h[n], dtu * Bf[n]);
            Av[n] *= dA;
        }
    }
    size_t o = (((size_t)c * 2 + b) * 1536 + d) * 16;
    #pragma unroll
    for (int k = 0; k < 4; ++k) {
        *(float4*)(chkA + o + k * 4) = make_float4(Av[4*k], Av[4*k+1], Av[4*k+2], Av[4*k+3]);
        *(float4*)(chkB + o + k * 4) = make_float4(h[4*k], h[4*k+1], h[4*k+2], h[4*k+3]);
    }
}

// ---------------- scan v3 pass 2: fold chunk summaries -> h_start ------------
__global__ void __launch_bounds__(256, 2) scan_comb_kernel(const float* __restrict__ chkA,
        const float* __restrict__ chkB, float* __restrict__ hstart) {
    int idx = blockIdx.x * 256 + threadIdx.x;  // b*1536+d, 0..3071
    float hs[16];
    #pragma unroll
    for (int n = 0; n < 16; ++n) hs[n] = 0.f;
    for (int c = 0; c < SCAN_P; ++c) {
        size_t o = ((size_t)c * 3072 + idx) * 16;
        #pragma unroll
        for (int k = 0; k < 4; ++k)
            *(float4*)(hstart + o + k * 4) = make_float4(hs[4*k], hs[4*k+1], hs[4*k+2], hs[4*k+3]);
        #pragma unroll
        for (int k = 0; k < 4; ++k) {
            float4 Ac = *(const float4*)(chkA + o + k * 4);
            float4 Bc = *(const float4*)(chkB + o + k * 4);
            hs[4*k]   = fmaf(Ac.x, hs[4*k],   Bc.x);
            hs[4*k+1] = fmaf(Ac.y, hs[4*k+1], Bc.y);
            hs[4*k+2] = fmaf(Ac.z, hs[4*k+2], Bc.z);
            hs[4*k+3] = fmaf(Ac.w, hs[4*k+3], Bc.w);
        }
    }
}

// ---------------- scan v3 pass 3: replay with h_start, emit y ----------------
__global__ void __launch_bounds__(256, 2) scan2_kernel(const u16* __restrict__ p,
        const float* __restrict__ dt, const float* __restrict__ u,
        const float* __restrict__ A_log, const float* __restrict__ Dskip,
        const float* __restrict__ hstart, float* __restrict__ y) {
    int d = blockIdx.x * 256 + threadIdx.x;
    int b = blockIdx.y, c = blockIdx.z;
    int t0 = c * SCAN_T;
    float a[16];
    #pragma unroll
    for (int n = 0; n < 16; ++n) a[n] = -__expf(A_log[d * 16 + n]);
    float Dsk = Dskip[d];
    const u16* pB = p + (size_t)(b * 1024 + t0) * OPAD + B0 + d * 16;
    const u16* pC = p + (size_t)(b * 1024 + t0) * OPAD + C0 + d * 16;
    const float* dtp = dt + (size_t)(b * 1024 + t0) * DI + d;
    const float* up  = u  + (size_t)(b * 1024 + t0) * DI + d;
    float* yp        = y  + (size_t)(b * 1024 + t0) * DI + d;
    uint4 Br[SPF][2], Cr[SPF][2]; float dtr[SPF], ur[SPF];
    #pragma unroll
    for (int i = 0; i < SPF; ++i) {
        Br[i][0] = *(const uint4*)(pB + (size_t)i * OPAD);
        Br[i][1] = *(const uint4*)(pB + (size_t)i * OPAD + 8);
        Cr[i][0] = *(const uint4*)(pC + (size_t)i * OPAD);
        Cr[i][1] = *(const uint4*)(pC + (size_t)i * OPAD + 8);
        dtr[i] = dtp[(size_t)i * DI];
        ur[i]  = up[(size_t)i * DI];
    }
    float h[16];
    {
        size_t o = ((size_t)c * 3072 + (size_t)b * 1536 + d) * 16;
        #pragma unroll
        for (int k = 0; k < 4; ++k) {
            float4 hv = *(const float4*)(hstart + o + k * 4);
            h[4*k] = hv.x; h[4*k+1] = hv.y; h[4*k+2] = hv.z; h[4*k+3] = hv.w;
        }
    }
    for (int t = 0; t < SCAN_T; ++t) {
        int s = t & (SPF - 1);
        uint4 b0 = Br[s][0], b1 = Br[s][1], c0 = Cr[s][0], c1 = Cr[s][1];
        float dtv = dtr[s], uv = ur[s];
        int tl = t + SPF < SCAN_T ? t + SPF : SCAN_T - 1;
        Br[s][0] = *(const uint4*)(pB + (size_t)tl * OPAD);
        Br[s][1] = *(const uint4*)(pB + (size_t)tl * OPAD + 8);
        Cr[s][0] = *(const uint4*)(pC + (size_t)tl * OPAD);
        Cr[s][1] = *(const uint4*)(pC + (size_t)tl * OPAD + 8);
        dtr[s] = dtp[(size_t)tl * DI];
        ur[s]  = up[(size_t)tl * DI];
        float Bf[16], Cf[16];
        unpack8(b0, Bf); unpack8(b1, Bf + 8);
        unpack8(c0, Cf); unpack8(c1, Cf + 8);
        float dtu = dtv * uv;
        #pragma unroll
        for (int n = 0; n < 16; ++n) {
            float dA = __expf(dtv * a[n]);
            h[n] = fmaf(dA, h[n], dtu * Bf[n]);
        }
        float a0 = fmaf(Cf[0], h[0], uv * Dsk), a1 = Cf[1] * h[1];
        float a2 = Cf[2] * h[2], a3 = Cf[3] * h[3];
        #pragma unroll
        for (int n = 4; n < 16; n += 4) {
            a0 = fmaf(Cf[n],   h[n],   a0);
            a1 = fmaf(Cf[n+1], h[n+1], a1);
            a2 = fmaf(Cf[n+2], h[n+2], a2);
            a3 = fmaf(Cf[n+3], h[n+3], a3);
        }
        yp[(size_t)t * DI] = (a0 + a1) + (a2 + a3);
    }
}

// ---------------- gating + RMSNorm + residual -> g (bf16) --------------------
__global__ void __launch_bounds__(256) gate_kernel(const u16* __restrict__ p,
        const float* __restrict__ y, const float* __restrict__ res,
        const float* __restrict__ norm_w, u16* __restrict__ g) {
    int m = blockIdx.x, tid = threadIdx.x;
    const u16* pz = p + (size_t)m * OPAD + Z0;
    const float* yr = y + (size_t)m * DI;
    float gp[6];
    float ss = 0.f, dummy = 0.f;
    #pragma unroll
    for (int i = 0; i < 6; ++i) {
        int d = i * 256 + tid;
        float z = bf2f(pz[d]);
        float gv = yr[d] * z / (1.f + __expf(-z));
        gp[i] = gv;
        ss += gv * gv;
    }
    block_reduce2(ss, dummy);
    float scale = rsqrtf(ss * (1.f / DI) + 1e-6f);
    #pragma unroll
    for (int i = 0; i < 6; ++i) {
        int d = i * 256 + tid;
        float val = gp[i] * scale * norm_w[d] + res[(size_t)m * DI + d];
        g[(size_t)m * DI + d] = f2bf(val);
    }
}

// ---------------- host ----------------
extern "C" void kernel_launch(void* const* d_in, const int* in_sizes, int n_in,
                              void* d_out, int out_size, void* d_ws, size_t ws_size,
                              hipStream_t stream) {
    const float* x       = (const float*)d_in[0];
    const float* ln_w    = (const float*)d_in[1];
    const float* ln_b    = (const float*)d_in[2];
    const float* W_in    = (const float*)d_in[3];
    const float* W_dt    = (const float*)d_in[4];
    const float* conv_w  = (const float*)d_in[5];
    const float* conv_b  = (const float*)d_in[6];
    const float* A_log   = (const float*)d_in[7];
    const float* Dskip   = (const float*)d_in[8];
    const float* dt_bias = (const float*)d_in[9];
    const float* norm_w  = (const float*)d_in[10];
    const float* W_res   = (const float*)d_in[11];
    const float* W_out   = (const float*)d_in[12];
    float* out = (float*)d_out;

    char* wsb = (char*)d_ws;
    u16* Wbf     = (u16*)(wsb + 0);           //  80,412,672  (OPAD*768*2)
    u16* Wresbf  = (u16*)(wsb + 80412672);    //   2,359,296
    u16* Woutbf  = (u16*)(wsb + 82771968);    //   2,359,296
    u16* xnbf    = (u16*)(wsb + 85131264);    //   3,145,728
    u16* xbf     = (u16*)(wsb + 88276992);    //   3,145,728
    u16* pbuf    = (u16*)(wsb + 91422720);    // 214,433,792  (2048*OPAD*2)
    float* ucv   = (float*)(wsb + 305856512); //  12,582,912
    float* dtv   = (float*)(wsb + 318439424); //  12,582,912
    float* ybuf  = (float*)(wsb + 331022336); //  12,582,912
    float* resb  = (float*)(wsb + 343605248); //  12,582,912
    u16* gbuf    = (u16*)(wsb + 356188160);   //   6,291,456  -> total 362,479,616
    // scan chunk buffers alias the Wbf region (dead after gemm1):
    float* chkA  = (float*)(wsb + 0);         //   6,291,456 (32*2*1536*16*4)
    float* chkB  = (float*)(wsb + 6291456);   //   6,291,456
    float* hst   = (float*)(wsb + 12582912);  //   6,291,456 (ends 18.9MB < 80.4MB)

    // 1) weight converts
    cvt_kernel<<<39264, 256, 0, stream>>>(W_in, Wbf, (long)OTOT * DM, (long)OPAD * DM);
    cvt_kernel<<<1152, 256, 0, stream>>>(W_res, Wresbf, (long)DI * DM, (long)DI * DM);
    cvt_kernel<<<1152, 256, 0, stream>>>(W_out, Woutbf, (long)DM * DI, (long)DM * DI);
    // 2) layernorm
    ln_kernel<<<2048, 256, 0, stream>>>(x, ln_w, ln_b, xnbf, xbf);
    // 3) big GEMM: p = xn @ W_in^T (bf16 out, ldc = OPAD); XCD-aware remap,
    //    grid 16 x 416 covers 16 x 409 tiles (7*16 blocks early-exit)
    gemm_bt<1, 1><<<dim3(16, 416), 256, 0, stream>>>(xnbf, Wbf, pbuf, DM, OPAD);
    // 4) res = x @ W_res^T (f32 out)
    gemm_bt<0, 0><<<dim3(16, 12), 256, 0, stream>>>(xbf, Wresbf, resb, DM, DI);
    // 5) conv
    conv_kernel<<<dim3(6, 2048), 256, 0, stream>>>(pbuf, conv_w, conv_b, ucv);
    // 6) dt
    dt_kernel<<<128, 256, 0, stream>>>(pbuf, W_dt, dt_bias, dtv);
    // 7) scan v3: chunk-parallel, lane-owns-d
    scan1_kernel<<<dim3(6, 2, SCAN_P), 256, 0, stream>>>(pbuf, dtv, ucv, A_log, chkA, chkB);
    scan_comb_kernel<<<12, 256, 0, stream>>>(chkA, chkB, hst);
    scan2_kernel<<<dim3(6, 2, SCAN_P), 256, 0, stream>>>(pbuf, dtv, ucv, A_log, Dskip, hst, ybuf);
    // 8) gate + rmsnorm + residual
    gate_kernel<<<2048, 256, 0, stream>>>(pbuf, ybuf, resb, norm_w, gbuf);
    // 9) out = g @ W_out^T (f32 out)
    gemm_bt<0, 0><<<dim3(16, 6), 256, 0, stream>>>(gbuf, Woutbf, out, DI, DM);
}

// Round 6
// 754.089 us; speedup vs baseline: 1.2114x; 1.2114x over previous
//
#include <hip/hip_runtime.h>

// HybridMambaBlock pipeline:
//  1) cvt: W_in/W_res/W_out f32 -> bf16 (W_in padded to OPAD rows, zero fill)
//  2) ln: LayerNorm(x) -> xn(bf16); also x -> bf16 for the residual GEMM
//  3) gemm_bt<bf16 out>: p = xn @ W_in^T   (2048 x 52352, the big one)
//  4) gemm_bt<f32 out>:  res = x @ W_res^T
//  5) conv: depthwise causal conv K=4 on u slice of p -> u_conv (f32)
//  6) dt: dt = clip(softplus(dth @ W_dt^T + bias), 1e-4, 1)
//  7) scan v3: chunk-parallel (P=32), lane-owns-d (h[16] in regs, no LDS)
//  8) gate: g = rmsnorm(y*silu(z))*norm_w + res -> bf16
//  9) gemm_bt<f32 out>: out = g @ W_out^T
//
// R5 fixes:
//  - gemm1: REVERTED the XCD remap (it regressed 217->240: read locality up
//    but write streaming destroyed). Back to plain grid x=m fastest (R4: 217).
//  - scan1/scan2: the scratch spill was caused by RUNTIME ring indices
//    (s = t&3 in a rolled loop -> private arrays lowered to scratch; VGPR=48,
//    scan2 WRITE 231MB). Restructured: outer t0 += SPF, inner s-loop fully
//    unrolled -> all ring indices compile-time -> arrays stay in VGPRs.

typedef unsigned short u16;
typedef __bf16 bf16x8 __attribute__((ext_vector_type(8)));
typedef float f32x4 __attribute__((ext_vector_type(4)));

#define OPAD 52352   // 409*128 >= 52272
#define OTOT 52272
#define DI   1536
#define DM   768
#define Z0   0
#define U0   1536
#define DTH0 3072
#define B0   3120
#define C0   27696

#define SCAN_P 32
#define SCAN_T 32    // 1024 / SCAN_P
#define SPF    4     // prefetch ring depth (must divide SCAN_T)

__device__ static inline u16 f2bf(float f) {
    unsigned u = __float_as_uint(f);
    u += 0x7fffu + ((u >> 16) & 1u);
    return (u16)(u >> 16);
}
__device__ static inline float bf2f(u16 s) {
    return __uint_as_float(((unsigned)s) << 16);
}

__device__ static inline void gload16(const void* g, void* l) {
    __builtin_amdgcn_global_load_lds(
        (const __attribute__((address_space(1))) unsigned int*)g,
        (__attribute__((address_space(3))) unsigned int*)l, 16, 0, 0);
}

// unpack 8 bf16 (as uint4) -> 8 f32, memory order preserved
__device__ static inline void unpack8(uint4 v, float* f) {
    unsigned w0 = v.x, w1 = v.y, w2 = v.z, w3 = v.w;
    f[0] = __uint_as_float(w0 << 16); f[1] = __uint_as_float(w0 & 0xffff0000u);
    f[2] = __uint_as_float(w1 << 16); f[3] = __uint_as_float(w1 & 0xffff0000u);
    f[4] = __uint_as_float(w2 << 16); f[5] = __uint_as_float(w2 & 0xffff0000u);
    f[6] = __uint_as_float(w3 << 16); f[7] = __uint_as_float(w3 & 0xffff0000u);
}

// ---------------- f32 -> bf16 convert (with zero pad to n_tot) ----------------
__global__ void cvt_kernel(const float* __restrict__ src, u16* __restrict__ dst,
                           long n_src, long n_tot) {
    long i4 = ((long)blockIdx.x * 256 + threadIdx.x) * 4;
    if (i4 >= n_tot) return;
    ushort4 o;
    if (i4 < n_src) {  // n_src is a multiple of 4 for all callers
        float4 v = *(const float4*)(src + i4);
        o.x = f2bf(v.x); o.y = f2bf(v.y); o.z = f2bf(v.z); o.w = f2bf(v.w);
    } else {
        o.x = o.y = o.z = o.w = 0;
    }
    *(ushort4*)(dst + i4) = o;
}

// ---------------- block reduce (sum of two values across 256 threads) --------
__device__ static inline void block_reduce2(float& a, float& b) {
    #pragma unroll
    for (int o = 32; o > 0; o >>= 1) {
        a += __shfl_down(a, o);
        b += __shfl_down(b, o);
    }
    __shared__ float sa[4], sb[4];
    int lane = threadIdx.x & 63, w = threadIdx.x >> 6;
    if (lane == 0) { sa[w] = a; sb[w] = b; }
    __syncthreads();
    a = sa[0] + sa[1] + sa[2] + sa[3];
    b = sb[0] + sb[1] + sb[2] + sb[3];
}

// ---------------- LayerNorm -> xn bf16, plus raw x -> bf16 -------------------
__global__ void __launch_bounds__(256) ln_kernel(const float* __restrict__ x,
        const float* __restrict__ w, const float* __restrict__ b,
        u16* __restrict__ xnbf, u16* __restrict__ xbf) {
    int m = blockIdx.x, tid = threadIdx.x;
    const float* xr = x + (size_t)m * DM;
    float v[3];
    v[0] = xr[tid]; v[1] = xr[tid + 256]; v[2] = xr[tid + 512];
    float s = v[0] + v[1] + v[2];
    float ss = v[0]*v[0] + v[1]*v[1] + v[2]*v[2];
    block_reduce2(s, ss);
    float mu = s * (1.f / DM);
    float var = ss * (1.f / DM) - mu * mu;
    float inv = rsqrtf(var + 1e-5f);
    #pragma unroll
    for (int i = 0; i < 3; ++i) {
        int d = tid + i * 256;
        float xn = (v[i] - mu) * inv * w[d] + b[d];
        xnbf[(size_t)m * DM + d] = f2bf(xn);
        xbf[(size_t)m * DM + d] = f2bf(v[i]);
    }
}

// ---------------- bf16 MFMA GEMM: C[M,N] = A[M,K] * B[N,K]^T -----------------
// 128x128 tile, BK=64, 256 threads (4 waves, each 64x64 via 4x4 of 16x16x32).
// Grid: x = m-tile (fastest -> W-slice reuse across co-resident m-tiles).
// LDS: XOR-swizzled 16B segments (gather-side permute) -> conflict-free reads.
template <int OUT_BF16>
__global__ void __launch_bounds__(256) gemm_bt(const u16* __restrict__ A,
        const u16* __restrict__ B, void* __restrict__ C, int K, int ldc) {
    __shared__ u16 smem[2 * 128 * 64];
    u16* As = smem;
    u16* Bs = smem + 128 * 64;
    int tid = threadIdx.x;
    int m0 = blockIdx.x * 128, n0 = blockIdx.y * 128;
    int lane = tid & 63, wave = tid >> 6;
    int wm = wave >> 1, wn = wave & 1;
    int l15 = lane & 15, l4 = lane >> 4;
    f32x4 acc[4][4] = {};
    const u16* Ag = A + (size_t)m0 * K;
    const u16* Bg = B + (size_t)n0 * K;
    int crow = tid >> 3;                              // 0..31: row within 32-row group
    int ccol = ((tid & 7) ^ ((tid >> 3) & 7)) * 8;    // swizzled 16B segment
    int ldsoff = (tid & 192) * 16;                    // wave*1024 bytes
    int xr = l15 & 7;                                 // read-side swizzle key

    for (int k0 = 0; k0 < K; k0 += 64) {
        __syncthreads();
        #pragma unroll
        for (int it = 0; it < 4; ++it) {
            gload16(Ag + (size_t)(it * 32 + crow) * K + k0 + ccol,
                    (char*)As + it * 4096 + ldsoff);
            gload16(Bg + (size_t)(it * 32 + crow) * K + k0 + ccol,
                    (char*)Bs + it * 4096 + ldsoff);
        }
        __syncthreads();
        const u16* Arow = As + (wm * 64 + l15) * 64;
        const u16* Brow = Bs + (wn * 64 + l15) * 64;
        #pragma unroll
        for (int kk8 = 0; kk8 < 8; kk8 += 4) {
            int sw = ((l4 + kk8) ^ xr) * 8;
            bf16x8 af[4], bfr[4];
            #pragma unroll
            for (int i = 0; i < 4; ++i) af[i] = *(const bf16x8*)(Arow + i * 16 * 64 + sw);
            #pragma unroll
            for (int j = 0; j < 4; ++j) bfr[j] = *(const bf16x8*)(Brow + j * 16 * 64 + sw);
            #pragma unroll
            for (int i = 0; i < 4; ++i)
                #pragma unroll
                for (int j = 0; j < 4; ++j)
                    acc[i][j] = __builtin_amdgcn_mfma_f32_16x16x32_bf16(
                        af[i], bfr[j], acc[i][j], 0, 0, 0);
        }
    }
    #pragma unroll
    for (int i = 0; i < 4; ++i) {
        int row = m0 + wm * 64 + i * 16 + l4 * 4;
        #pragma unroll
        for (int j = 0; j < 4; ++j) {
            int col = n0 + wn * 64 + j * 16 + l15;
            #pragma unroll
            for (int r = 0; r < 4; ++r) {
                size_t off = (size_t)(row + r) * ldc + col;
                if (OUT_BF16) ((u16*)C)[off] = f2bf(acc[i][j][r]);
                else          ((float*)C)[off] = acc[i][j][r];
            }
        }
    }
}

// ---------------- depthwise causal conv (K=4) --------------------------------
__global__ void __launch_bounds__(256) conv_kernel(const u16* __restrict__ p,
        const float* __restrict__ cw, const float* __restrict__ cb,
        float* __restrict__ u) {
    int d = blockIdx.x * 256 + threadIdx.x;  // 0..1535
    int m = blockIdx.y;                      // 0..2047
    int l = m & 1023;
    int bm = m - l;                          // b*1024
    float acc = cb[d];
    #pragma unroll
    for (int j = 0; j < 4; ++j) {
        int ls = l - 3 + j;
        if (ls >= 0)
            acc += cw[d * 4 + j] * bf2f(p[(size_t)(bm + ls) * OPAD + U0 + d]);
    }
    u[(size_t)m * DI + d] = acc;
}

// ---------------- dt = clip(softplus(dth @ W_dt^T + bias)) -------------------
__global__ void __launch_bounds__(256) dt_kernel(const u16* __restrict__ p,
        const float* __restrict__ Wdt, const float* __restrict__ dt_bias,
        float* __restrict__ dt) {
    int m0 = blockIdx.x * 16, tid = threadIdx.x;
    __shared__ float dth_s[16 * 48];
    for (int i = tid; i < 16 * 48; i += 256)
        dth_s[i] = bf2f(p[(size_t)(m0 + i / 48) * OPAD + DTH0 + (i % 48)]);
    __syncthreads();
    #pragma unroll
    for (int ii = 0; ii < 6; ++ii) {
        int d = ii * 256 + tid;
        float base = dt_bias[d];
        float acc[16];
        #pragma unroll
        for (int mm = 0; mm < 16; ++mm) acc[mm] = base;
        for (int r = 0; r < 48; ++r) {
            float wv = Wdt[d * 48 + r];
            #pragma unroll
            for (int mm = 0; mm < 16; ++mm)
                acc[mm] = fmaf(wv, dth_s[mm * 48 + r], acc[mm]);
        }
        #pragma unroll
        for (int mm = 0; mm < 16; ++mm) {
            float xv = acc[mm];
            float sp = xv > 20.f ? xv : log1pf(__expf(xv));
            sp = fminf(fmaxf(sp, 1e-4f), 1.0f);
            dt[(size_t)(m0 + mm) * DI + d] = sp;
        }
    }
}

// ---------------- scan v3 pass 1: per-chunk (A,h) summaries ------------------
// Lane owns one d-channel; h[16]/A[16] in regs; B reads are per-lane 32B
// contiguous dwordx4 pairs (coalesced across lanes). Prefetch ring with
// COMPILE-TIME indices (inner s-loop fully unrolled) so it stays in VGPRs.
__global__ void __launch_bounds__(256, 2) scan1_kernel(const u16* __restrict__ p,
        const float* __restrict__ dt, const float* __restrict__ u,
        const float* __restrict__ A_log,
        float* __restrict__ chkA, float* __restrict__ chkB) {
    int d = blockIdx.x * 256 + threadIdx.x;
    int b = blockIdx.y, c = blockIdx.z;
    int t0base = c * SCAN_T;
    float a[16];
    #pragma unroll
    for (int n = 0; n < 16; ++n) a[n] = -__expf(A_log[d * 16 + n]);
    const u16* pB = p + (size_t)(b * 1024 + t0base) * OPAD + B0 + d * 16;
    const float* dtp = dt + (size_t)(b * 1024 + t0base) * DI + d;
    const float* up  = u  + (size_t)(b * 1024 + t0base) * DI + d;
    uint4 Br[SPF][2]; float dtr[SPF], ur[SPF];
    #pragma unroll
    for (int i = 0; i < SPF; ++i) {
        Br[i][0] = *(const uint4*)(pB + (size_t)i * OPAD);
        Br[i][1] = *(const uint4*)(pB + (size_t)i * OPAD + 8);
        dtr[i] = dtp[(size_t)i * DI];
        ur[i]  = up[(size_t)i * DI];
    }
    float h[16], Av[16];
    #pragma unroll
    for (int n = 0; n < 16; ++n) { h[n] = 0.f; Av[n] = 1.f; }
    for (int t0 = 0; t0 < SCAN_T; t0 += SPF) {
        #pragma unroll
        for (int s = 0; s < SPF; ++s) {
            int t = t0 + s;
            uint4 b0 = Br[s][0], b1 = Br[s][1];
            float dtv = dtr[s], uv = ur[s];
            int tl = t + SPF < SCAN_T ? t + SPF : SCAN_T - 1;
            Br[s][0] = *(const uint4*)(pB + (size_t)tl * OPAD);
            Br[s][1] = *(const uint4*)(pB + (size_t)tl * OPAD + 8);
            dtr[s] = dtp[(size_t)tl * DI];
            ur[s]  = up[(size_t)tl * DI];
            float Bf[16];
            unpack8(b0, Bf); unpack8(b1, Bf + 8);
            float dtu = dtv * uv;
            #pragma unroll
            for (int n = 0; n < 16; ++n) {
                float dA = __expf(dtv * a[n]);
                h[n] = fmaf(dA, h[n], dtu * Bf[n]);
                Av[n] *= dA;
            }
        }
    }
    size_t o = (((size_t)c * 2 + b) * 1536 + d) * 16;
    #pragma unroll
    for (int k = 0; k < 4; ++k) {
        *(float4*)(chkA + o + k * 4) = make_float4(Av[4*k], Av[4*k+1], Av[4*k+2], Av[4*k+3]);
        *(float4*)(chkB + o + k * 4) = make_float4(h[4*k], h[4*k+1], h[4*k+2], h[4*k+3]);
    }
}

// ---------------- scan v3 pass 2: fold chunk summaries -> h_start ------------
__global__ void __launch_bounds__(256) scan_comb_kernel(const float* __restrict__ chkA,
        const float* __restrict__ chkB, float* __restrict__ hstart) {
    int idx = blockIdx.x * 256 + threadIdx.x;  // b*1536+d, 0..3071
    float hs[16];
    #pragma unroll
    for (int n = 0; n < 16; ++n) hs[n] = 0.f;
    for (int c = 0; c < SCAN_P; ++c) {
        size_t o = ((size_t)c * 3072 + idx) * 16;
        #pragma unroll
        for (int k = 0; k < 4; ++k)
            *(float4*)(hstart + o + k * 4) = make_float4(hs[4*k], hs[4*k+1], hs[4*k+2], hs[4*k+3]);
        #pragma unroll
        for (int k = 0; k < 4; ++k) {
            float4 Ac = *(const float4*)(chkA + o + k * 4);
            float4 Bc = *(const float4*)(chkB + o + k * 4);
            hs[4*k]   = fmaf(Ac.x, hs[4*k],   Bc.x);
            hs[4*k+1] = fmaf(Ac.y, hs[4*k+1], Bc.y);
            hs[4*k+2] = fmaf(Ac.z, hs[4*k+2], Bc.z);
            hs[4*k+3] = fmaf(Ac.w, hs[4*k+3], Bc.w);
        }
    }
}

// ---------------- scan v3 pass 3: replay with h_start, emit y ----------------
__global__ void __launch_bounds__(256, 2) scan2_kernel(const u16* __restrict__ p,
        const float* __restrict__ dt, const float* __restrict__ u,
        const float* __restrict__ A_log, const float* __restrict__ Dskip,
        const float* __restrict__ hstart, float* __restrict__ y) {
    int d = blockIdx.x * 256 + threadIdx.x;
    int b = blockIdx.y, c = blockIdx.z;
    int t0base = c * SCAN_T;
    float a[16];
    #pragma unroll
    for (int n = 0; n < 16; ++n) a[n] = -__expf(A_log[d * 16 + n]);
    float Dsk = Dskip[d];
    const u16* pB = p + (size_t)(b * 1024 + t0base) * OPAD + B0 + d * 16;
    const u16* pC = p + (size_t)(b * 1024 + t0base) * OPAD + C0 + d * 16;
    const float* dtp = dt + (size_t)(b * 1024 + t0base) * DI + d;
    const float* up  = u  + (size_t)(b * 1024 + t0base) * DI + d;
    float* yp        = y  + (size_t)(b * 1024 + t0base) * DI + d;
    uint4 Br[SPF][2], Cr[SPF][2]; float dtr[SPF], ur[SPF];
    #pragma unroll
    for (int i = 0; i < SPF; ++i) {
        Br[i][0] = *(const uint4*)(pB + (size_t)i * OPAD);
        Br[i][1] = *(const uint4*)(pB + (size_t)i * OPAD + 8);
        Cr[i][0] = *(const uint4*)(pC + (size_t)i * OPAD);
        Cr[i][1] = *(const uint4*)(pC + (size_t)i * OPAD + 8);
        dtr[i] = dtp[(size_t)i * DI];
        ur[i]  = up[(size_t)i * DI];
    }
    float h[16];
    {
        size_t o = ((size_t)c * 3072 + (size_t)b * 1536 + d) * 16;
        #pragma unroll
        for (int k = 0; k < 4; ++k) {
            float4 hv = *(const float4*)(hstart + o + k * 4);
            h[4*k] = hv.x; h[4*k+1] = hv.y; h[4*k+2] = hv.z; h[4*k+3] = hv.w;
        }
    }
    for (int t0 = 0; t0 < SCAN_T; t0 += SPF) {
        #pragma unroll
        for (int s = 0; s < SPF; ++s) {
            int t = t0 + s;
            uint4 b0 = Br[s][0], b1 = Br[s][1], c0 = Cr[s][0], c1 = Cr[s][1];
            float dtv = dtr[s], uv = ur[s];
            int tl = t + SPF < SCAN_T ? t + SPF : SCAN_T - 1;
            Br[s][0] = *(const uint4*)(pB + (size_t)tl * OPAD);
            Br[s][1] = *(const uint4*)(pB + (size_t)tl * OPAD + 8);
            Cr[s][0] = *(const uint4*)(pC + (size_t)tl * OPAD);
            Cr[s][1] = *(const uint4*)(pC + (size_t)tl * OPAD + 8);
            dtr[s] = dtp[(size_t)tl * DI];
            ur[s]  = up[(size_t)tl * DI];
            float Bf[16], Cf[16];
            unpack8(b0, Bf); unpack8(b1, Bf + 8);
            unpack8(c0, Cf); unpack8(c1, Cf + 8);
            float dtu = dtv * uv;
            #pragma unroll
            for (int n = 0; n < 16; ++n) {
                float dA = __expf(dtv * a[n]);
                h[n] = fmaf(dA, h[n], dtu * Bf[n]);
            }
            float a0 = fmaf(Cf[0], h[0], uv * Dsk), a1 = Cf[1] * h[1];
            float a2 = Cf[2] * h[2], a3 = Cf[3] * h[3];
            #pragma unroll
            for (int n = 4; n < 16; n += 4) {
                a0 = fmaf(Cf[n],   h[n],   a0);
                a1 = fmaf(Cf[n+1], h[n+1], a1);
                a2 = fmaf(Cf[n+2], h[n+2], a2);
                a3 = fmaf(Cf[n+3], h[n+3], a3);
            }
            yp[(size_t)t * DI] = (a0 + a1) + (a2 + a3);
        }
    }
}

// ---------------- gating + RMSNorm + residual -> g (bf16) --------------------
__global__ void __launch_bounds__(256) gate_kernel(const u16* __restrict__ p,
        const float* __restrict__ y, const float* __restrict__ res,
        const float* __restrict__ norm_w, u16* __restrict__ g) {
    int m = blockIdx.x, tid = threadIdx.x;
    const u16* pz = p + (size_t)m * OPAD + Z0;
    const float* yr = y + (size_t)m * DI;
    float gp[6];
    float ss = 0.f, dummy = 0.f;
    #pragma unroll
    for (int i = 0; i < 6; ++i) {
        int d = i * 256 + tid;
        float z = bf2f(pz[d]);
        float gv = yr[d] * z / (1.f + __expf(-z));
        gp[i] = gv;
        ss += gv * gv;
    }
    block_reduce2(ss, dummy);
    float scale = rsqrtf(ss * (1.f / DI) + 1e-6f);
    #pragma unroll
    for (int i = 0; i < 6; ++i) {
        int d = i * 256 + tid;
        float val = gp[i] * scale * norm_w[d] + res[(size_t)m * DI + d];
        g[(size_t)m * DI + d] = f2bf(val);
    }
}

// ---------------- host ----------------
extern "C" void kernel_launch(void* const* d_in, const int* in_sizes, int n_in,
                              void* d_out, int out_size, void* d_ws, size_t ws_size,
                              hipStream_t stream) {
    const float* x       = (const float*)d_in[0];
    const float* ln_w    = (const float*)d_in[1];
    const float* ln_b    = (const float*)d_in[2];
    const float* W_in    = (const float*)d_in[3];
    const float* W_dt    = (const float*)d_in[4];
    const float* conv_w  = (const float*)d_in[5];
    const float* conv_b  = (const float*)d_in[6];
    const float* A_log   = (const float*)d_in[7];
    const float* Dskip   = (const float*)d_in[8];
    const float* dt_bias = (const float*)d_in[9];
    const float* norm_w  = (const float*)d_in[10];
    const float* W_res   = (const float*)d_in[11];
    const float* W_out   = (const float*)d_in[12];
    float* out = (float*)d_out;

    char* wsb = (char*)d_ws;
    u16* Wbf     = (u16*)(wsb + 0);           //  80,412,672  (OPAD*768*2)
    u16* Wresbf  = (u16*)(wsb + 80412672);    //   2,359,296
    u16* Woutbf  = (u16*)(wsb + 82771968);    //   2,359,296
    u16* xnbf    = (u16*)(wsb + 85131264);    //   3,145,728
    u16* xbf     = (u16*)(wsb + 88276992);    //   3,145,728
    u16* pbuf    = (u16*)(wsb + 91422720);    // 214,433,792  (2048*OPAD*2)
    float* ucv   = (float*)(wsb + 305856512); //  12,582,912
    float* dtv   = (float*)(wsb + 318439424); //  12,582,912
    float* ybuf  = (float*)(wsb + 331022336); //  12,582,912
    float* resb  = (float*)(wsb + 343605248); //  12,582,912
    u16* gbuf    = (u16*)(wsb + 356188160);   //   6,291,456  -> total 362,479,616
    // scan chunk buffers alias the Wbf region (dead after gemm1):
    float* chkA  = (float*)(wsb + 0);         //   6,291,456 (32*2*1536*16*4)
    float* chkB  = (float*)(wsb + 6291456);   //   6,291,456
    float* hst   = (float*)(wsb + 12582912);  //   6,291,456 (ends 18.9MB < 80.4MB)

    // 1) weight converts
    cvt_kernel<<<39264, 256, 0, stream>>>(W_in, Wbf, (long)OTOT * DM, (long)OPAD * DM);
    cvt_kernel<<<1152, 256, 0, stream>>>(W_res, Wresbf, (long)DI * DM, (long)DI * DM);
    cvt_kernel<<<1152, 256, 0, stream>>>(W_out, Woutbf, (long)DM * DI, (long)DM * DI);
    // 2) layernorm
    ln_kernel<<<2048, 256, 0, stream>>>(x, ln_w, ln_b, xnbf, xbf);
    // 3) big GEMM: p = xn @ W_in^T (bf16 out, ldc = OPAD); grid x=m, y=n
    gemm_bt<1><<<dim3(16, 409), 256, 0, stream>>>(xnbf, Wbf, pbuf, DM, OPAD);
    // 4) res = x @ W_res^T (f32 out)
    gemm_bt<0><<<dim3(16, 12), 256, 0, stream>>>(xbf, Wresbf, resb, DM, DI);
    // 5) conv
    conv_kernel<<<dim3(6, 2048), 256, 0, stream>>>(pbuf, conv_w, conv_b, ucv);
    // 6) dt
    dt_kernel<<<128, 256, 0, stream>>>(pbuf, W_dt, dt_bias, dtv);
    // 7) scan v3: chunk-parallel, lane-owns-d
    scan1_kernel<<<dim3(6, 2, SCAN_P), 256, 0, stream>>>(pbuf, dtv, ucv, A_log, chkA, chkB);
    scan_comb_kernel<<<12, 256, 0, stream>>>(chkA, chkB, hst);
    scan2_kernel<<<dim3(6, 2, SCAN_P), 256, 0, stream>>>(pbuf, dtv, ucv, A_log, Dskip, hst, ybuf);
    // 8) gate + rmsnorm + residual
    gate_kernel<<<2048, 256, 0, stream>>>(pbuf, ybuf, resb, norm_w, gbuf);
    // 9) out = g @ W_out^T (f32 out)
    gemm_bt<0><<<dim3(16, 6), 256, 0, stream>>>(gbuf, Woutbf, out, DI, DM);
}